// Round 8
// baseline (428.263 us; speedup 1.0000x reference)
//
#include <hip/hip_runtime.h>
#include <hip/hip_bf16.h>

// Problem constants
#define B_  64
#define C_  64
#define T_  300
#define V_  25
#define O_  128
#define TV  (T_*V_)     // 7500
#define BTV (B_*T_*V_)  // 480000
#define NPF 9600        // fuse blocks: 64 b x 150 tgroups (2 t-slabs each)

typedef __bf16 bf16x8 __attribute__((ext_vector_type(8)));
typedef float f32x4 __attribute__((ext_vector_type(4)));

// ---- ws layout (byte offsets); proven ws >= 198MB ----
#define WSB_APW   0ull            // padded A-powers [i*25+j][28] f32 = 22400 (slot 22528)
#define WSB_WT    22528ull        // Wt[256][64] bf16 linear = 32768 -> 55296
#define WSB_PSC   55296ull        // [9600][128] f32 = 4,915,200
#define WSB_PSQ   4970496ull      // same
#define WSB_P2C   9885696ull      // [128][128] f32 = 65,536
#define WSB_P2Q   9951232ull
#define WSB_SCL   10016768ull     // 128 f32 (slot 512)
#define WSB_SFT   10017280ull
#define WSB_Y     10017792ull     // [BTV][128] bf16 = 122,880,000
#define WS_NEED2  132897792ull

static __device__ __forceinline__ unsigned short f2bf(float f) {
    unsigned int u = __float_as_uint(f);
    unsigned int r = (u + 0x7fffu + ((u >> 16) & 1u)) >> 16;
    return (unsigned short)r;
}
static __device__ __forceinline__ unsigned int pk2bf(float a, float b) {
    return (unsigned int)f2bf(a) | ((unsigned int)f2bf(b) << 16);
}
static __device__ __forceinline__ float bf2f(unsigned short u) {
    return __uint_as_float(((unsigned int)u) << 16);
}

// ---------------- A powers, padded layout apw[(i*25+j)*28 + k] = A^{i+1}[j,k] ----
__global__ __launch_bounds__(256) void k_apow2(const float* __restrict__ A,
                                               float* __restrict__ apw) {
    __shared__ float P[2][625];
    const int tid = threadIdx.x;
    for (int p = tid; p < 625; p += 256) P[0][p] = A[p];
    for (int idx = tid; idx < 5632; idx += 256) apw[idx] = 0.f;
    __syncthreads();
    int cur = 0;
    for (int i = 0; i < 8; i++) {
        if (i > 0) {
            for (int p = tid; p < 625; p += 256) {
                int r = p / 25, c2 = p - r * 25;
                float s = 0.f;
                #pragma unroll 5
                for (int j = 0; j < 25; j++) s = fmaf(P[cur][r*25 + j], A[j*25 + c2], s);
                P[cur ^ 1][p] = s;
            }
            __syncthreads();
            cur ^= 1;
        }
        for (int p = tid; p < 625; p += 256) {
            int r = p / 25, c2 = p - r * 25;
            apw[(i * 25 + r) * 28 + c2] = P[cur][p];
        }
        __syncthreads();
    }
}

// ---------------- Wt[oc][c] bf16 LINEAR; oc<128 -> W, else Wr ----------------
__global__ __launch_bounds__(256) void k_wt(const float* __restrict__ W,
                                            const float* __restrict__ Wr,
                                            unsigned short* __restrict__ Wt) {
    const int oc = threadIdx.x;
    const float* src = (oc < 128) ? (W + oc * 64) : (Wr + (oc - 128) * 64);
    unsigned short row[64];
    #pragma unroll
    for (int c = 0; c < 64; c++) row[c] = f2bf(src[c]);
    #pragma unroll
    for (int cc = 0; cc < 8; cc++)
        *(uint4*)(Wt + oc * 64 + cc * 8) = *(uint4*)(row + cc * 8);
}

// ---------------- fused: x->H (MFMA, in LDS) -> graph-apply + residual + BN + Y ----
// block: 256 thr (4 waves), 2 t-slabs (50 rows). 4 blocks/CU (35.6 KB LDS, <=128 VGPR).
__global__ __launch_bounds__(256, 4) void k_fuse(const float* __restrict__ x,
                                                 const unsigned short* __restrict__ Wt,
                                                 const float* __restrict__ apw_g,
                                                 unsigned short* __restrict__ Yg,
                                                 float* __restrict__ psc,
                                                 float* __restrict__ psq) {
    __shared__ __align__(16) unsigned short As[64 * 64];    // 8 KB  (rows 50..63 zero)
    __shared__ __align__(16) unsigned short Hs[50 * 256];   // 25.6 KB
    __shared__ float ps[256], qs[256];                      // 2 KB
    const int tg = blockIdx.x, b = blockIdx.y;              // tg 0..149
    const int t0 = tg * 2;
    const int tid = threadIdx.x, wv = tid >> 6, ln = tid & 63;

    // stage x -> As bf16 [row=tv_local(0..49)][c], chunk-XOR swizzled by row&7
    for (int q = tid; q < 1600; q += 256) {
        int c = q / 25, e = q - c * 25;                     // e = float2 index
        float2 f = *(const float2*)(x + ((size_t)(b * 64 + c)) * TV + t0 * 25 + e * 2);
        int r0 = e * 2;
        As[r0 * 64 + (((c >> 3) ^ (r0 & 7)) << 3) + (c & 7)]           = f2bf(f.x);
        As[(r0+1) * 64 + (((c >> 3) ^ ((r0+1) & 7)) << 3) + (c & 7)]   = f2bf(f.y);
    }
    // zero pad rows 50..63 (dwords 1600..2047)
    for (int w = tid; w < 448; w += 256) ((unsigned int*)As)[1600 + w] = 0u;
    __syncthreads();

    // MFMA: H[64][256] = As(64x64) . Wt^T ; wave = 64 rows x 64 oc (wv = oc quarter)
    f32x4 acc[4][4] = {};
    #pragma unroll
    for (int ks = 0; ks < 2; ks++) {
        // bv loaded per-ks to cap live registers (L1-resident Wt)
        const unsigned short* wb = Wt + (wv * 64 + (ln & 15)) * 64 + (ln >> 4) * 8 + ks * 32;
        bf16x8 bv[4], af[4];
        #pragma unroll
        for (int ni = 0; ni < 4; ni++) bv[ni] = *(const bf16x8*)(wb + ni * 1024);
        #pragma unroll
        for (int mi = 0; mi < 4; mi++) {
            int row = mi * 16 + (ln & 15);
            af[mi] = *(const bf16x8*)(As + row * 64 + (((ks * 4 + (ln >> 4)) ^ (row & 7)) << 3));
        }
        #pragma unroll
        for (int mi = 0; mi < 4; mi++)
            #pragma unroll
            for (int ni = 0; ni < 4; ni++)
                acc[mi][ni] = __builtin_amdgcn_mfma_f32_16x16x32_bf16(bv[ni], af[mi], acc[mi][ni], 0, 0, 0);
    }
    // epilogue: H -> Hs bf16, chunk-swizzled (co ^ row&7), rows < 50
    #pragma unroll
    for (int mi = 0; mi < 4; mi++) {
        int row = mi * 16 + (ln & 15);
        if (row < 50) {
            #pragma unroll
            for (int ni = 0; ni < 4; ni++) {
                int co = wv * 64 + ni * 16 + (ln >> 4) * 4;
                int addr = row * 256 + (((co >> 3) ^ (row & 7)) << 3) + (co & 7);
                uint2 d;
                d.x = pk2bf(acc[mi][ni][0], acc[mi][ni][1]);
                d.y = pk2bf(acc[mi][ni][2], acc[mi][ni][3]);
                *(uint2*)(Hs + addr) = d;
            }
        }
    }
    __syncthreads();

    // phase 2: thread = (s = tid>>7, o = tid&127); A-powers direct from global (L1)
    const int s = tid >> 7;
    const int o = tid & 127;
    const float* Ai = apw_g + (o >> 4) * 700;       // branch = o>>4, 700 = 25*28
    float a[25];
    // init with residual: H[s*25+k][128+o]
    #pragma unroll
    for (int k = 0; k < 25; k++) {
        int row = s * 25 + k, co = 128 + o;
        a[k] = bf2f(Hs[row * 256 + (((co >> 3) ^ (row & 7)) << 3) + (co & 7)]);
    }
    for (int j = 0; j < 25; j++) {
        int row = s * 25 + j;
        float h = bf2f(Hs[row * 256 + (((o >> 3) ^ (row & 7)) << 3) + (o & 7)]);
        const float4* ar = (const float4*)(Ai + j * 28);
        #pragma unroll
        for (int qd = 0; qd < 6; qd++) {
            float4 av = ar[qd];
            a[qd*4+0] = fmaf(h, av.x, a[qd*4+0]);
            a[qd*4+1] = fmaf(h, av.y, a[qd*4+1]);
            a[qd*4+2] = fmaf(h, av.z, a[qd*4+2]);
            a[qd*4+3] = fmaf(h, av.w, a[qd*4+3]);
        }
        float4 a6 = ar[6];                           // floats 24..27 (pad zeroed)
        a[24] = fmaf(h, a6.x, a[24]);
    }
    // BN partials + Y store (layout [btk][o] -> perfectly coalesced)
    float s0 = 0.f, q0 = 0.f;
    unsigned short* yb = Yg + ((size_t)((b * 300 + t0 + s) * 25)) * 128 + o;
    #pragma unroll
    for (int k = 0; k < 25; k++) {
        s0 += a[k]; q0 += a[k] * a[k];
        yb[k * 128] = f2bf(a[k]);
    }
    ps[tid] = s0; qs[tid] = q0;
    __syncthreads();
    if (tid < 128) {
        const int blk = b * 150 + tg;
        psc[(size_t)blk * 128 + tid] = ps[tid] + ps[tid + 128];
        psq[(size_t)blk * 128 + tid] = qs[tid] + qs[tid + 128];
    }
}

// ---------------- stage-1 reduction: 9600 -> 128 partials per o ----------------
__global__ __launch_bounds__(256) void k_red1(const float* __restrict__ psc,
                                              const float* __restrict__ psq,
                                              float* __restrict__ p2c,
                                              float* __restrict__ p2q) {
    const int r = blockIdx.x;              // 0..127, covers i = r*75 .. +74
    const int tid = threadIdx.x;
    const int o = tid & 127;
    const float* src = (tid < 128) ? psc : psq;
    float* dst = (tid < 128) ? p2c : p2q;
    float S = 0.f;
    for (int ii = 0; ii < 75; ii++)
        S += src[(size_t)(r * 75 + ii) * 128 + o];
    dst[r * 128 + o] = S;
}

// ---------------- finalize BN ----------------
__global__ void k_fin(const float* __restrict__ p2c, const float* __restrict__ p2q,
                      const float* __restrict__ gamma, const float* __restrict__ beta,
                      float* __restrict__ scale, float* __restrict__ shift) {
    const int o = threadIdx.x;
    if (o >= 128) return;
    float S = 0.f, Q = 0.f;
    for (int r = 0; r < 128; r++) { S += p2c[r * 128 + o]; Q += p2q[r * 128 + o]; }
    float inv = 1.f / (float)BTV;
    float mean = S * inv;
    float var = Q * inv - mean * mean;
    float sc = gamma[o] / sqrtf(var + 1e-5f);
    scale[o] = sc;
    shift[o] = beta[o] - mean * sc;
}

// ---------------- norm: Y[btk][o] bf16 -> out[b,o,t,k] f32 (LDS transpose) ------
__global__ __launch_bounds__(256) void k_norm3(const unsigned short* __restrict__ Yg,
                                               const float* __restrict__ scale,
                                               const float* __restrict__ shift,
                                               float* __restrict__ out) {
    __shared__ __align__(16) unsigned short Ls[100 * 128];   // 25.6 KB
    const int m = blockIdx.x, b = blockIdx.y;                // m: 4-t chunk (0..74)
    const int t0 = m * 4;
    const int tid = threadIdx.x;
    const size_t g0 = (size_t)(b * 300 + t0) * 25;           // 100 global rows
    // stage: 100 rows x 16 uint4, swizzle chunk by row&15
    for (int idx = tid; idx < 1600; idx += 256) {
        int r = idx >> 4, c16 = idx & 15;
        uint4 d = *(const uint4*)(Yg + (g0 + r) * 128 + c16 * 8);
        *(uint4*)(Ls + r * 128 + ((c16 ^ (r & 15)) << 3)) = d;
    }
    __syncthreads();
    const int o = tid & 127, q0 = tid >> 7;
    const float sc = scale[o], sh = shift[o];
    float* ob = out + ((size_t)(b * 128 + o) * 300 + t0) * 25;
    for (int q = q0; q < 25; q += 2) {
        float4 d;
        float* dp = (float*)&d;
        #pragma unroll
        for (int e = 0; e < 4; e++) {
            int mr = q * 4 + e;
            unsigned short v = Ls[mr * 128 + (((o >> 3) ^ (mr & 15)) << 3) + (o & 7)];
            dp[e] = fmaxf(fmaf(bf2f(v), sc, sh), 0.f);
        }
        *(float4*)(ob + q * 4) = d;
    }
}

extern "C" void kernel_launch(void* const* d_in, const int* in_sizes, int n_in,
                              void* d_out, int out_size, void* d_ws, size_t ws_size,
                              hipStream_t stream) {
    const float* x     = (const float*)d_in[0];
    const float* A     = (const float*)d_in[1];
    const float* W     = (const float*)d_in[2];
    const float* Wr    = (const float*)d_in[3];
    const float* gamma = (const float*)d_in[5];
    const float* beta  = (const float*)d_in[6];
    float* out = (float*)d_out;
    char* wsb  = (char*)d_ws;
    if (ws_size < (size_t)WS_NEED2) return;

    float*          apw = (float*)(wsb + WSB_APW);
    unsigned short* Wt  = (unsigned short*)(wsb + WSB_WT);
    float*          psc = (float*)(wsb + WSB_PSC);
    float*          psq = (float*)(wsb + WSB_PSQ);
    float*          p2c = (float*)(wsb + WSB_P2C);
    float*          p2q = (float*)(wsb + WSB_P2Q);
    float*          scl = (float*)(wsb + WSB_SCL);
    float*          sft = (float*)(wsb + WSB_SFT);
    unsigned short* Y   = (unsigned short*)(wsb + WSB_Y);

    k_apow2<<<1, 256, 0, stream>>>(A, apw);
    k_wt<<<1, 256, 0, stream>>>(W, Wr, Wt);
    k_fuse<<<dim3(150, 64), 256, 0, stream>>>(x, Wt, apw, Y, psc, psq);
    k_red1<<<128, 256, 0, stream>>>(psc, psq, p2c, p2q);
    k_fin<<<1, 128, 0, stream>>>(p2c, p2q, gamma, beta, scl, sft);
    k_norm3<<<dim3(75, 64), 256, 0, stream>>>(Y, scl, sft, out);
}

// Round 9
// 282.746 us; speedup vs baseline: 1.5147x; 1.5147x over previous
//
#include <hip/hip_runtime.h>
#include <hip/hip_bf16.h>

// Problem constants
#define B_  64
#define C_  64
#define T_  300
#define V_  25
#define O_  128
#define TV  (T_*V_)     // 7500
#define BTV (B_*T_*V_)  // 480000
#define NPF 4800        // fuse blocks: 64 b x 75 tgroups (4 slabs each)
#define HS_STRIDE 258   // LDS H row stride (shorts): conflict-free gather

typedef __bf16 bf16x8 __attribute__((ext_vector_type(8)));
typedef float f32x4 __attribute__((ext_vector_type(4)));

// ---- ws layout (byte offsets); proven ws >= 198MB ----
#define WSB_AF    0ull           // A-fragment table [18][64][8] bf16 = 18432
#define WSB_WT    18432ull       // Wt[256][64] bf16 linear = 32768 -> 51200
#define WSB_PSC   51200ull       // [4800][128] f32 = 2,457,600 -> 2,508,800
#define WSB_PSQ   2508800ull     // -> 4,966,400
#define WSB_P2C   4966400ull     // [96][128] f32 = 49152
#define WSB_P2Q   5015552ull
#define WSB_SCL   5064704ull
#define WSB_SFT   5065216ull
#define WSB_Y     5065728ull     // [BTV][128] bf16 = 122,880,000
#define WS_NEED2  127945728ull

static __device__ __forceinline__ unsigned short f2bf(float f) {
    unsigned int u = __float_as_uint(f);
    unsigned int r = (u + 0x7fffu + ((u >> 16) & 1u)) >> 16;
    return (unsigned short)r;
}
static __device__ __forceinline__ unsigned int pk2bf(float a, float b) {
    return (unsigned int)f2bf(a) | ((unsigned int)f2bf(b) << 16);
}
static __device__ __forceinline__ float bf2f(unsigned short u) {
    return __uint_as_float(((unsigned int)u) << 16);
}

// ---------------- A powers -> MFMA A-fragment table ----------------
// AF[fi][lane][e] bf16: fi<16: branch i=fi>>1, mt=fi&1: val = A^{i+1}[j][k],
//   j=(lane>>4)*8+e, k=mt*16+(lane&15), zero if j>=25||k>=25.
// fi=16,17: identity fragments (val = (j==k)).
__global__ __launch_bounds__(256) void k_apow2(const float* __restrict__ A,
                                               unsigned short* __restrict__ AF) {
    __shared__ float Pall[8][625];
    const int tid = threadIdx.x;
    for (int p = tid; p < 625; p += 256) Pall[0][p] = A[p];
    __syncthreads();
    for (int i = 1; i < 8; i++) {
        for (int p = tid; p < 625; p += 256) {
            int r = p / 25, c = p - r * 25;
            float s = 0.f;
            #pragma unroll 5
            for (int j = 0; j < 25; j++) s = fmaf(Pall[i-1][r*25 + j], A[j*25 + c], s);
            Pall[i][p] = s;
        }
        __syncthreads();
    }
    for (int idx = tid; idx < 18 * 64; idx += 256) {
        int fi = idx >> 6, l = idx & 63, qq = l >> 4, tt = l & 15;
        unsigned short v[8];
        #pragma unroll
        for (int e = 0; e < 8; e++) {
            int j = qq * 8 + e;
            float val = 0.f;
            if (fi < 16) {
                int i = fi >> 1, k = (fi & 1) * 16 + tt;
                if (j < 25 && k < 25) val = Pall[i][j * 25 + k];
            } else {
                int k = (fi - 16) * 16 + tt;
                if (j < 25 && k < 25 && j == k) val = 1.f;
            }
            v[e] = f2bf(val);
        }
        *(uint4*)(AF + idx * 8) = *(uint4*)v;
    }
}

// ---------------- Wt[oc][c] bf16 LINEAR; oc<128 -> W, else Wr ----------------
__global__ __launch_bounds__(256) void k_wt(const float* __restrict__ W,
                                            const float* __restrict__ Wr,
                                            unsigned short* __restrict__ Wt) {
    const int oc = threadIdx.x;
    const float* src = (oc < 128) ? (W + oc * 64) : (Wr + (oc - 128) * 64);
    unsigned short row[64];
    #pragma unroll
    for (int c = 0; c < 64; c++) row[c] = f2bf(src[c]);
    #pragma unroll
    for (int cc = 0; cc < 8; cc++)
        *(uint4*)(Wt + oc * 64 + cc * 8) = *(uint4*)(row + cc * 8);
}

// ---------------- fused: x->H (MFMA) -> graph-apply (MFMA) + residual + BN + Y ----
// block: 256 thr (4 waves), 4 slabs (100 rows). 2 blocks/CU (73 KB LDS).
__global__ __launch_bounds__(256, 2) void k_fuse(const float* __restrict__ x,
                                                 const unsigned short* __restrict__ Wt,
                                                 const unsigned short* __restrict__ AF,
                                                 unsigned short* __restrict__ Yg,
                                                 float* __restrict__ psc,
                                                 float* __restrict__ psq) {
    __shared__ __align__(16) unsigned short SM[8192 + 110 * HS_STRIDE];  // As | Hs
    unsigned short* As = SM;
    unsigned short* Hs = SM + 8192;
    const int tg = blockIdx.x, b = blockIdx.y;          // tg 0..74 (4 t-slabs)
    const int tid = threadIdx.x, wv = tid >> 6, ln = tid & 63;
    const int q = ln >> 4, t = ln & 15;

    // stage x -> As bf16 [row=tv_local(0..99)][c], chunk-XOR swizzled by row&7
    for (int p = tid; p < 1600; p += 256) {
        int c = p / 25, e4 = p - c * 25;
        float4 f = *(const float4*)(x + ((size_t)(b * 64 + c)) * TV + tg * 100 + e4 * 4);
        float vv[4] = { f.x, f.y, f.z, f.w };
        #pragma unroll
        for (int u = 0; u < 4; u++) {
            int r = e4 * 4 + u;
            As[r * 64 + (((c >> 3) ^ (r & 7)) << 3) + (c & 7)] = f2bf(vv[u]);
        }
    }
    // zero As pad rows 100..111 (dwords 3200..3583)
    for (int w = tid; w < 384; w += 256) ((unsigned int*)As)[3200 + w] = 0u;
    // zero Hs pad rows 100..109 (gathers j>=25 from s=3 read here; must be finite)
    for (int w = tid; w < 1290; w += 256) ((unsigned int*)Hs)[12900 + w] = 0u;
    __syncthreads();

    // phase 1: H[112 rows][256 oc] = As . Wt^T ; wave = oc quarter (64 oc)
    f32x4 acc[7][4] = {};
    #pragma unroll
    for (int ks = 0; ks < 2; ks++) {
        const unsigned short* wb = Wt + (wv * 64 + t) * 64 + q * 8 + ks * 32;
        bf16x8 bv[4], af[7];
        #pragma unroll
        for (int ni = 0; ni < 4; ni++) bv[ni] = *(const bf16x8*)(wb + ni * 1024);
        #pragma unroll
        for (int mi = 0; mi < 7; mi++) {
            int row = mi * 16 + t;
            af[mi] = *(const bf16x8*)(As + row * 64 + (((ks * 4 + q) ^ (row & 7)) << 3));
        }
        #pragma unroll
        for (int mi = 0; mi < 7; mi++)
            #pragma unroll
            for (int ni = 0; ni < 4; ni++)
                acc[mi][ni] = __builtin_amdgcn_mfma_f32_16x16x32_bf16(bv[ni], af[mi], acc[mi][ni], 0, 0, 0);
    }
    // epilogue: H -> Hs[row][oc] (u32-pair writes, 4-aligned)
    #pragma unroll
    for (int mi = 0; mi < 7; mi++) {
        int row = mi * 16 + t;
        if (row < 100) {
            #pragma unroll
            for (int ni = 0; ni < 4; ni++) {
                int co = wv * 64 + ni * 16 + q * 4;
                unsigned int* dst = (unsigned int*)(Hs + row * HS_STRIDE + co);
                dst[0] = pk2bf(acc[mi][ni][0], acc[mi][ni][1]);
                dst[1] = pk2bf(acc[mi][ni][2], acc[mi][ni][3]);
            }
        }
    }
    __syncthreads();

    // phase 2: wave = slab s; per branch i: D[k][o] = sum_j A^i[j][k] H[j][o] + H[k][128+o]
    const int s = wv;
    const bf16x8* AFp = (const bf16x8*)AF;
    const bf16x8 id0 = AFp[16 * 64 + ln];
    const bf16x8 id1 = AFp[17 * 64 + ln];
    f32x4 acc2[8][2];
    #pragma unroll
    for (int i = 0; i < 8; i++) { acc2[i][0] = (f32x4){0,0,0,0}; acc2[i][1] = (f32x4){0,0,0,0}; }
    const int rowq = (s * 25 + q * 8) * HS_STRIDE + t;
    #pragma unroll
    for (int i = 0; i < 8; i++) {
        unsigned short hm[8], hr[8];
        #pragma unroll
        for (int e = 0; e < 8; e++) {
            int a = rowq + e * HS_STRIDE + i * 16;
            hm[e] = Hs[a];
            hr[e] = Hs[a + 128];
        }
        bf16x8 bm = *(bf16x8*)hm;
        bf16x8 brs = *(bf16x8*)hr;
        bf16x8 a0 = AFp[(i * 2 + 0) * 64 + ln];
        bf16x8 a1 = AFp[(i * 2 + 1) * 64 + ln];
        acc2[i][0] = __builtin_amdgcn_mfma_f32_16x16x32_bf16(id0, brs, acc2[i][0], 0, 0, 0);
        acc2[i][1] = __builtin_amdgcn_mfma_f32_16x16x32_bf16(id1, brs, acc2[i][1], 0, 0, 0);
        acc2[i][0] = __builtin_amdgcn_mfma_f32_16x16x32_bf16(a0, bm, acc2[i][0], 0, 0, 0);
        acc2[i][1] = __builtin_amdgcn_mfma_f32_16x16x32_bf16(a1, bm, acc2[i][1], 0, 0, 0);
    }
    // per-o BN partials (k>=25 D slots are exact zeros)
    float* ps = (float*)SM;            // As region dead
    float* qs = ps + 512;
    #pragma unroll
    for (int i = 0; i < 8; i++) {
        float si = 0.f, qi = 0.f;
        #pragma unroll
        for (int mt = 0; mt < 2; mt++)
            #pragma unroll
            for (int r = 0; r < 4; r++) {
                float v = acc2[i][mt][r];
                si += v; qi += v * v;
            }
        si += __shfl_xor(si, 16); si += __shfl_xor(si, 32);
        qi += __shfl_xor(qi, 16); qi += __shfl_xor(qi, 32);
        if (ln < 16) { ps[s * 128 + i * 16 + t] = si; qs[s * 128 + i * 16 + t] = qi; }
    }
    // D -> own-slab Hs rows as Y-tile [k][o]
    #pragma unroll
    for (int i = 0; i < 8; i++)
        #pragma unroll
        for (int mt = 0; mt < 2; mt++)
            #pragma unroll
            for (int r = 0; r < 4; r++) {
                int k = mt * 16 + q * 4 + r;
                if (k < 25)
                    Hs[(s * 25 + k) * HS_STRIDE + i * 16 + t] = f2bf(acc2[i][mt][r]);
            }
    __syncthreads();
    if (tid < 128) {
        float S = ps[tid] + ps[128 + tid] + ps[256 + tid] + ps[384 + tid];
        float Q = qs[tid] + qs[128 + tid] + qs[256 + tid] + qs[384 + tid];
        int blk = b * 75 + tg;
        psc[(size_t)blk * 128 + tid] = S;
        psq[(size_t)blk * 128 + tid] = Q;
    }
    // Y[(btk)][o]: 100 rows x 128 shorts, coalesced uint4
    const size_t yrow0 = (size_t)(b * 75 + tg) * 100;
    for (int idx = tid; idx < 1600; idx += 256) {
        int row = idx >> 4, c16 = idx & 15;
        const unsigned int* sp = (const unsigned int*)(Hs + row * HS_STRIDE + c16 * 8);
        uint4 d; d.x = sp[0]; d.y = sp[1]; d.z = sp[2]; d.w = sp[3];
        *(uint4*)(Yg + (yrow0 + row) * 128 + c16 * 8) = d;
    }
}

// ---------------- stage-1 reduction: 4800 -> 96 partials per o ----------------
__global__ __launch_bounds__(256) void k_red1(const float* __restrict__ psc,
                                              const float* __restrict__ psq,
                                              float* __restrict__ p2c,
                                              float* __restrict__ p2q) {
    const int r = blockIdx.x;              // 0..95, covers 50 blocks each
    const int tid = threadIdx.x;
    const int o = tid & 127;
    const float* src = (tid < 128) ? psc : psq;
    float* dst = (tid < 128) ? p2c : p2q;
    float S = 0.f;
    for (int ii = 0; ii < 50; ii++)
        S += src[(size_t)(r * 50 + ii) * 128 + o];
    dst[r * 128 + o] = S;
}

// ---------------- finalize BN ----------------
__global__ void k_fin(const float* __restrict__ p2c, const float* __restrict__ p2q,
                      const float* __restrict__ gamma, const float* __restrict__ beta,
                      float* __restrict__ scale, float* __restrict__ shift) {
    const int o = threadIdx.x;
    if (o >= 128) return;
    float S = 0.f, Q = 0.f;
    for (int r = 0; r < 96; r++) { S += p2c[r * 128 + o]; Q += p2q[r * 128 + o]; }
    float inv = 1.f / (float)BTV;
    float mean = S * inv;
    float var = Q * inv - mean * mean;
    float sc = gamma[o] / sqrtf(var + 1e-5f);
    scale[o] = sc;
    shift[o] = beta[o] - mean * sc;
}

// ---------------- norm: Y[btk][o] bf16 -> out[b,o,t,k] f32 (LDS transpose) ------
__global__ __launch_bounds__(256) void k_norm3(const unsigned short* __restrict__ Yg,
                                               const float* __restrict__ scale,
                                               const float* __restrict__ shift,
                                               float* __restrict__ out) {
    __shared__ __align__(16) unsigned short Ls[100 * 128];   // 25.6 KB
    const int m = blockIdx.x, b = blockIdx.y;                // m: 4-t chunk (0..74)
    const int t0 = m * 4;
    const int tid = threadIdx.x;
    const size_t g0 = (size_t)(b * 300 + t0) * 25;           // 100 global rows
    for (int idx = tid; idx < 1600; idx += 256) {
        int r = idx >> 4, c16 = idx & 15;
        uint4 d = *(const uint4*)(Yg + (g0 + r) * 128 + c16 * 8);
        *(uint4*)(Ls + r * 128 + ((c16 ^ (r & 15)) << 3)) = d;
    }
    __syncthreads();
    const int o = tid & 127, q0 = tid >> 7;
    const float sc = scale[o], sh = shift[o];
    float* ob = out + ((size_t)(b * 128 + o) * 300 + t0) * 25;
    for (int qq = q0; qq < 25; qq += 2) {
        float4 d;
        float* dp = (float*)&d;
        #pragma unroll
        for (int e = 0; e < 4; e++) {
            int mr = qq * 4 + e;
            unsigned short v = Ls[mr * 128 + (((o >> 3) ^ (mr & 15)) << 3) + (o & 7)];
            dp[e] = fmaxf(fmaf(bf2f(v), sc, sh), 0.f);
        }
        *(float4*)(ob + qq * 4) = d;
    }
}

extern "C" void kernel_launch(void* const* d_in, const int* in_sizes, int n_in,
                              void* d_out, int out_size, void* d_ws, size_t ws_size,
                              hipStream_t stream) {
    const float* x     = (const float*)d_in[0];
    const float* A     = (const float*)d_in[1];
    const float* W     = (const float*)d_in[2];
    const float* Wr    = (const float*)d_in[3];
    const float* gamma = (const float*)d_in[5];
    const float* beta  = (const float*)d_in[6];
    float* out = (float*)d_out;
    char* wsb  = (char*)d_ws;
    if (ws_size < (size_t)WS_NEED2) return;

    unsigned short* AF  = (unsigned short*)(wsb + WSB_AF);
    unsigned short* Wt  = (unsigned short*)(wsb + WSB_WT);
    float*          psc = (float*)(wsb + WSB_PSC);
    float*          psq = (float*)(wsb + WSB_PSQ);
    float*          p2c = (float*)(wsb + WSB_P2C);
    float*          p2q = (float*)(wsb + WSB_P2Q);
    float*          scl = (float*)(wsb + WSB_SCL);
    float*          sft = (float*)(wsb + WSB_SFT);
    unsigned short* Y   = (unsigned short*)(wsb + WSB_Y);

    k_apow2<<<1, 256, 0, stream>>>(A, AF);
    k_wt<<<1, 256, 0, stream>>>(W, Wr, Wt);
    k_fuse<<<dim3(75, 64), 256, 0, stream>>>(x, Wt, AF, Y, psc, psq);
    k_red1<<<96, 256, 0, stream>>>(psc, psq, p2c, p2q);
    k_fin<<<1, 128, 0, stream>>>(p2c, p2q, gamma, beta, scl, sft);
    k_norm3<<<dim3(75, 64), 256, 0, stream>>>(Y, scl, sft, out);
}

// Round 10
// 220.285 us; speedup vs baseline: 1.9441x; 1.2835x over previous
//
#include <hip/hip_runtime.h>
#include <hip/hip_bf16.h>

// Problem constants
#define B_  64
#define C_  64
#define T_  300
#define V_  25
#define O_  128
#define TV  (T_*V_)     // 7500
#define BTV (B_*T_*V_)  // 480000
#define NPF 4800        // fuse blocks: 64 b x 75 tgroups (4 slabs each)
#define HS_STRIDE 258   // LDS H row stride (shorts): conflict-free gather (129 dw ≡ 1 mod 32)
#define HS_ROWS 107     // 100 + 7 pad rows (gather j<=31 from slab 3 base 75)

typedef __bf16 bf16x8 __attribute__((ext_vector_type(8)));
typedef float f32x4 __attribute__((ext_vector_type(4)));

// ---- ws layout (byte offsets); proven ws >= 198MB ----
#define WSB_AF    0ull           // A-fragment table [18][64][8] bf16 = 18432
#define WSB_WT    18432ull       // Wt[256][64] bf16 linear = 32768 -> 51200
#define WSB_PSC   51200ull       // [4800][128] f32 -> slot 2,457,600
#define WSB_PSQ   2508800ull
#define WSB_P2C   4966400ull     // [96][128] f32
#define WSB_P2Q   5015552ull
#define WSB_SCL   5064704ull
#define WSB_SFT   5065216ull
#define WSB_Y     5065728ull     // [B*128][7500] bf16 = 122,880,000
#define WS_NEED2  127945728ull

static __device__ __forceinline__ unsigned short f2bf(float f) {
    unsigned int u = __float_as_uint(f);
    unsigned int r = (u + 0x7fffu + ((u >> 16) & 1u)) >> 16;
    return (unsigned short)r;
}
static __device__ __forceinline__ float bf2f(unsigned short u) {
    return __uint_as_float(((unsigned int)u) << 16);
}

// ---------------- prep: block 0 = A-power MFMA fragment table; block 1 = Wt ----
__global__ __launch_bounds__(256) void k_prep(const float* __restrict__ A,
                                              const float* __restrict__ W,
                                              const float* __restrict__ Wr,
                                              unsigned short* __restrict__ AF,
                                              unsigned short* __restrict__ Wt) {
    const int tid = threadIdx.x;
    if (blockIdx.x == 0) {
        __shared__ float Pall[8][625];
        for (int p = tid; p < 625; p += 256) Pall[0][p] = A[p];
        __syncthreads();
        for (int i = 1; i < 8; i++) {
            for (int p = tid; p < 625; p += 256) {
                int r = p / 25, c = p - r * 25;
                float s = 0.f;
                #pragma unroll 5
                for (int j = 0; j < 25; j++) s = fmaf(Pall[i-1][r*25 + j], A[j*25 + c], s);
                Pall[i][p] = s;
            }
            __syncthreads();
        }
        // AF[fi][lane][e]: fi<16: A^{i+1}[j][k], j=(l>>4)*8+e, k=(fi&1)*16+(l&15); fi=16,17: identity
        for (int idx = tid; idx < 18 * 64; idx += 256) {
            int fi = idx >> 6, l = idx & 63, qq = l >> 4, tt = l & 15;
            unsigned short v[8];
            #pragma unroll
            for (int e = 0; e < 8; e++) {
                int j = qq * 8 + e;
                float val = 0.f;
                if (fi < 16) {
                    int i = fi >> 1, k = (fi & 1) * 16 + tt;
                    if (j < 25 && k < 25) val = Pall[i][j * 25 + k];
                } else {
                    int k = (fi - 16) * 16 + tt;
                    if (j < 25 && k < 25 && j == k) val = 1.f;
                }
                v[e] = f2bf(val);
            }
            *(uint4*)(AF + idx * 8) = *(uint4*)v;
        }
    } else {
        const int oc = tid;
        const float* src = (oc < 128) ? (W + oc * 64) : (Wr + (oc - 128) * 64);
        unsigned short row[64];
        #pragma unroll
        for (int c = 0; c < 64; c++) row[c] = f2bf(src[c]);
        #pragma unroll
        for (int cc = 0; cc < 8; cc++)
            *(uint4*)(Wt + oc * 64 + cc * 8) = *(uint4*)(row + cc * 8);
    }
}

// ---------------- fused: x->H (MFMA) -> graph-apply (MFMA) + residual + BN + Y ----
// block: 512 thr (8 waves), 4 slabs (100 rows). 2 blocks/CU (71.6 KB LDS), 16 waves/CU.
__global__ __launch_bounds__(512, 2) void k_fuse(const float* __restrict__ x,
                                                 const unsigned short* __restrict__ Wt,
                                                 const unsigned short* __restrict__ AF,
                                                 unsigned short* __restrict__ Yg,
                                                 float* __restrict__ psc,
                                                 float* __restrict__ psq) {
    __shared__ __align__(16) unsigned short SM[8192 + HS_ROWS * HS_STRIDE];  // As | Hs
    unsigned short* As = SM;
    unsigned short* Hs = SM + 8192;
    const int tg = blockIdx.x, b = blockIdx.y;          // tg 0..74 (4 t-slabs)
    const int tid = threadIdx.x, wv = tid >> 6, ln = tid & 63;
    const int q = ln >> 4, t = ln & 15;

    // stage x -> As bf16 [row=tv_local(0..99)][c], chunk-XOR swizzled by row&7
    for (int p = tid; p < 1600; p += 512) {
        int c = p / 25, e4 = p - c * 25;
        float4 f = *(const float4*)(x + ((size_t)(b * 64 + c)) * TV + tg * 100 + e4 * 4);
        float vv[4] = { f.x, f.y, f.z, f.w };
        #pragma unroll
        for (int u = 0; u < 4; u++) {
            int r = e4 * 4 + u;
            As[r * 64 + (((c >> 3) ^ (r & 7)) << 3) + (c & 7)] = f2bf(vv[u]);
        }
    }
    // zero As pad rows 100..127 (dwords 3200..4095)
    for (int w = tid; w < 896; w += 512) ((unsigned int*)As)[3200 + w] = 0u;
    // zero Hs pad rows 100..106 (903 dwords)
    for (int w = tid; w < 903; w += 512) ((unsigned int*)Hs)[12900 + w] = 0u;
    __syncthreads();

    // phase 1: H[128 rows][256 oc] = As . Wt^T ; wave = (rowblock rb, oc-quad oq)
    {
        const int rb = wv >> 2, oq = wv & 3;
        f32x4 acc[4][4] = {};
        #pragma unroll
        for (int ks = 0; ks < 2; ks++) {
            const unsigned short* wb = Wt + (oq * 64 + t) * 64 + q * 8 + ks * 32;
            bf16x8 bv[4], af[4];
            #pragma unroll
            for (int ni = 0; ni < 4; ni++) bv[ni] = *(const bf16x8*)(wb + ni * 1024);
            #pragma unroll
            for (int mi = 0; mi < 4; mi++) {
                int row = rb * 64 + mi * 16 + t;
                af[mi] = *(const bf16x8*)(As + row * 64 + (((ks * 4 + q) ^ (row & 7)) << 3));
            }
            #pragma unroll
            for (int mi = 0; mi < 4; mi++)
                #pragma unroll
                for (int ni = 0; ni < 4; ni++)
                    acc[mi][ni] = __builtin_amdgcn_mfma_f32_16x16x32_bf16(bv[ni], af[mi], acc[mi][ni], 0, 0, 0);
        }
        // epilogue: H -> Hs[row][oc] (u32-pair writes; Hs odd rows are 4B-aligned only)
        #pragma unroll
        for (int mi = 0; mi < 4; mi++) {
            int row = rb * 64 + mi * 16 + t;
            if (row < 100) {
                #pragma unroll
                for (int ni = 0; ni < 4; ni++) {
                    int co = oq * 64 + ni * 16 + q * 4;
                    unsigned int* dst = (unsigned int*)(Hs + row * HS_STRIDE + co);
                    dst[0] = (unsigned int)f2bf(acc[mi][ni][0]) | ((unsigned int)f2bf(acc[mi][ni][1]) << 16);
                    dst[1] = (unsigned int)f2bf(acc[mi][ni][2]) | ((unsigned int)f2bf(acc[mi][ni][3]) << 16);
                }
            }
        }
    }
    __syncthreads();

    // phase 2: wave = (slab s, branch-half bh); i = bh*4+ii
    const int s = wv >> 1, bh = wv & 1;
    const bf16x8* AFp = (const bf16x8*)AF;
    const bf16x8 id0 = AFp[16 * 64 + ln];
    const bf16x8 id1 = AFp[17 * 64 + ln];
    f32x4 acc2[4][2];
    #pragma unroll
    for (int ii = 0; ii < 4; ii++) { acc2[ii][0] = (f32x4){0,0,0,0}; acc2[ii][1] = (f32x4){0,0,0,0}; }
    const int rowq = (s * 25 + q * 8) * HS_STRIDE + t;
    #pragma unroll
    for (int ii = 0; ii < 4; ii++) {
        const int i = bh * 4 + ii;
        unsigned short hm[8], hr[8];
        #pragma unroll
        for (int e = 0; e < 8; e++) {
            int a = rowq + e * HS_STRIDE + i * 16;
            hm[e] = Hs[a];
            hr[e] = Hs[a + 128];
        }
        bf16x8 bm = *(bf16x8*)hm;
        bf16x8 brs = *(bf16x8*)hr;
        bf16x8 a0 = AFp[(i * 2 + 0) * 64 + ln];
        bf16x8 a1 = AFp[(i * 2 + 1) * 64 + ln];
        acc2[ii][0] = __builtin_amdgcn_mfma_f32_16x16x32_bf16(id0, brs, acc2[ii][0], 0, 0, 0);
        acc2[ii][1] = __builtin_amdgcn_mfma_f32_16x16x32_bf16(id1, brs, acc2[ii][1], 0, 0, 0);
        acc2[ii][0] = __builtin_amdgcn_mfma_f32_16x16x32_bf16(a0, bm, acc2[ii][0], 0, 0, 0);
        acc2[ii][1] = __builtin_amdgcn_mfma_f32_16x16x32_bf16(a1, bm, acc2[ii][1], 0, 0, 0);
    }
    // per-o BN partials (k>=25 slots are exact zeros); waves write disjoint (s, o-half)
    float* ps = (float*)SM;            // As region dead
    float* qs = ps + 512;
    #pragma unroll
    for (int ii = 0; ii < 4; ii++) {
        float si = 0.f, qi = 0.f;
        #pragma unroll
        for (int mt = 0; mt < 2; mt++)
            #pragma unroll
            for (int r = 0; r < 4; r++) {
                float v = acc2[ii][mt][r];
                si += v; qi += v * v;
            }
        si += __shfl_xor(si, 16); si += __shfl_xor(si, 32);
        qi += __shfl_xor(qi, 16); qi += __shfl_xor(qi, 32);
        if (ln < 16) {
            ps[s * 128 + (bh * 4 + ii) * 16 + t] = si;
            qs[s * 128 + (bh * 4 + ii) * 16 + t] = qi;
        }
    }
    // D -> own-slab Hs rows (own column half; disjoint from other wave's reads)
    #pragma unroll
    for (int ii = 0; ii < 4; ii++)
        #pragma unroll
        for (int mt = 0; mt < 2; mt++)
            #pragma unroll
            for (int r = 0; r < 4; r++) {
                int k = mt * 16 + q * 4 + r;
                if (k < 25)
                    Hs[(s * 25 + k) * HS_STRIDE + (bh * 4 + ii) * 16 + t] = f2bf(acc2[ii][mt][r]);
            }
    __syncthreads();
    if (tid < 128) {
        float S = ps[tid] + ps[128 + tid] + ps[256 + tid] + ps[384 + tid];
        float Q = qs[tid] + qs[128 + tid] + qs[256 + tid] + qs[384 + tid];
        int blk = b * 75 + tg;
        psc[(size_t)blk * 128 + tid] = S;
        psq[(size_t)blk * 128 + tid] = Q;
    }
    // Y write, linear [b*128+o][7500]: lane runs of 25 -> 200B-coalesced uint2 stores
    for (int idx = tid; idx < 3200; idx += 512) {
        int o = idx / 25, w = idx - o * 25;           // w = uint2 chunk (4 shorts)
        unsigned short vv[4];
        #pragma unroll
        for (int e = 0; e < 4; e++)
            vv[e] = Hs[(w * 4 + e) * HS_STRIDE + o];  // local row tk = s*25+k = w*4+e
        uint2 d;
        d.x = (unsigned int)vv[0] | ((unsigned int)vv[1] << 16);
        d.y = (unsigned int)vv[2] | ((unsigned int)vv[3] << 16);
        *(uint2*)(Yg + (size_t)(b * 128 + o) * TV + tg * 100 + w * 4) = d;
    }
}

// ---------------- stage-1 reduction: 4800 -> 96 partials per o ----------------
__global__ __launch_bounds__(256) void k_red1(const float* __restrict__ psc,
                                              const float* __restrict__ psq,
                                              float* __restrict__ p2c,
                                              float* __restrict__ p2q) {
    const int r = blockIdx.x;
    const int tid = threadIdx.x;
    const int o = tid & 127;
    const float* src = (tid < 128) ? psc : psq;
    float* dst = (tid < 128) ? p2c : p2q;
    float S = 0.f;
    for (int ii = 0; ii < 50; ii++)
        S += src[(size_t)(r * 50 + ii) * 128 + o];
    dst[r * 128 + o] = S;
}

// ---------------- finalize BN ----------------
__global__ void k_fin(const float* __restrict__ p2c, const float* __restrict__ p2q,
                      const float* __restrict__ gamma, const float* __restrict__ beta,
                      float* __restrict__ scale, float* __restrict__ shift) {
    const int o = threadIdx.x;
    if (o >= 128) return;
    float S = 0.f, Q = 0.f;
    for (int r = 0; r < 96; r++) { S += p2c[r * 128 + o]; Q += p2q[r * 128 + o]; }
    float inv = 1.f / (float)BTV;
    float mean = S * inv;
    float var = Q * inv - mean * mean;
    float sc = gamma[o] / sqrtf(var + 1e-5f);
    scale[o] = sc;
    shift[o] = beta[o] - mean * sc;
}

// ---------------- norm: Y[bo][7500] bf16 -> out f32, fully linear both sides ----
__global__ __launch_bounds__(256) void k_norm2(const unsigned short* __restrict__ Y,
                                               const float* __restrict__ scale,
                                               const float* __restrict__ shift,
                                               float* __restrict__ out) {
    size_t e0 = ((size_t)blockIdx.x * 256 + threadIdx.x) * 8;
    #pragma unroll
    for (int g = 0; g < 2; g++) {
        size_t e = e0 + (size_t)g * 4;
        int o = (int)((e / 7500) & 127);
        float sc = scale[o], sh = shift[o];
        uint2 v = *(const uint2*)(Y + e);
        float4 d;
        d.x = fmaxf(fmaf(bf2f((unsigned short)(v.x & 0xffffu)), sc, sh), 0.f);
        d.y = fmaxf(fmaf(bf2f((unsigned short)(v.x >> 16)),     sc, sh), 0.f);
        d.z = fmaxf(fmaf(bf2f((unsigned short)(v.y & 0xffffu)), sc, sh), 0.f);
        d.w = fmaxf(fmaf(bf2f((unsigned short)(v.y >> 16)),     sc, sh), 0.f);
        *(float4*)(out + e) = d;
    }
}

extern "C" void kernel_launch(void* const* d_in, const int* in_sizes, int n_in,
                              void* d_out, int out_size, void* d_ws, size_t ws_size,
                              hipStream_t stream) {
    const float* x     = (const float*)d_in[0];
    const float* A     = (const float*)d_in[1];
    const float* W     = (const float*)d_in[2];
    const float* Wr    = (const float*)d_in[3];
    const float* gamma = (const float*)d_in[5];
    const float* beta  = (const float*)d_in[6];
    float* out = (float*)d_out;
    char* wsb  = (char*)d_ws;
    if (ws_size < (size_t)WS_NEED2) return;

    unsigned short* AF  = (unsigned short*)(wsb + WSB_AF);
    unsigned short* Wt  = (unsigned short*)(wsb + WSB_WT);
    float*          psc = (float*)(wsb + WSB_PSC);
    float*          psq = (float*)(wsb + WSB_PSQ);
    float*          p2c = (float*)(wsb + WSB_P2C);
    float*          p2q = (float*)(wsb + WSB_P2Q);
    float*          scl = (float*)(wsb + WSB_SCL);
    float*          sft = (float*)(wsb + WSB_SFT);
    unsigned short* Y   = (unsigned short*)(wsb + WSB_Y);

    k_prep<<<2, 256, 0, stream>>>(A, W, Wr, AF, Wt);
    k_fuse<<<dim3(75, 64), 512, 0, stream>>>(x, Wt, AF, Y, psc, psq);
    k_red1<<<96, 256, 0, stream>>>(psc, psq, p2c, p2q);
    k_fin<<<1, 128, 0, stream>>>(p2c, p2q, gamma, beta, scl, sft);
    k_norm2<<<30000, 256, 0, stream>>>(Y, scl, sft, out);
}